// Round 4
// baseline (351.939 us; speedup 1.0000x reference)
//
#include <hip/hip_runtime.h>
#include <math.h>
#include <stdint.h>

#define S_LEN   512
#define HORIZON 64
#define T_LEN   (S_LEN + HORIZON)
#define F_IN    4
#define IN_DIM  36   // F_IN + E
#define HID     32

typedef float v2f __attribute__((ext_vector_type(2)));

__device__ __forceinline__ float frcp(float x) { return __builtin_amdgcn_rcpf(x); }
__device__ __forceinline__ float fsig(float x) {
    return frcp(1.f + __expf(-x));
}
__device__ __forceinline__ float ftanh(float x) {
    float e = __expf(2.f * x);
    return (e - 1.f) * frcp(e + 1.f);
}
__device__ __forceinline__ float rdlane(float v, int l) {
    return __int_as_float(__builtin_amdgcn_readlane(__float_as_int(v), l));
}
// pack two wave-uniform floats into an SGPR pair (register placement only)
__device__ __forceinline__ double mk2(float a, float b) {
    union { float f[2]; double d; } u;
    u.f[0] = a; u.f[1] = b;
    return u.d;
}
// packed fma with the broadcast operand in SGPRs (1 scalar operand: legal)
__device__ __forceinline__ void pk_fma_s(v2f& acc, v2f w, double h2) {
    asm("v_pk_fma_f32 %0, %1, %2, %0" : "+v"(acc) : "v"(w), "s"(h2));
}

// DPP move with old=0.
#define DPP0(x, ctrl, rmask, bmask, bc) \
    __int_as_float(__builtin_amdgcn_update_dpp(0, __float_as_int(x), (ctrl), (rmask), (bmask), (bc)))

// ============ Kernel 1: the sequential recurrence (one wave) ============
// Interleaved layout: lane 2j+p: p==0 -> rows i[j], g[j]; p==1 -> rows f[j], o[j].
// h[j], c[j] valid at even lanes (odd lanes carry bounded garbage, never read).
__global__ __launch_bounds__(64, 1) void deepar_seq(
    const float* __restrict__ X,    const float* __restrict__ y,
    const float* __restrict__ Xf,   const float* __restrict__ eps,
    const float* __restrict__ W_ye, const float* __restrict__ b_ye,
    const float* __restrict__ W_ih, const float* __restrict__ W_hh,
    const float* __restrict__ b_ih, const float* __restrict__ b_hh,
    const float* __restrict__ W_ef, const float* __restrict__ b_ef,
    const float* __restrict__ W_av, const float* __restrict__ b_av,
    const float* __restrict__ W_out, const float* __restrict__ b_out,
    const float* __restrict__ W_mu, const float* __restrict__ b_mu,
    const float* __restrict__ W_sig, const float* __restrict__ b_sig,
    float* __restrict__ out, float* __restrict__ hist)
{
    const int lane = threadIdx.x;
    const int j    = lane >> 1;
    const int p    = lane & 1;
    const int r0   = j + 32 * p;
    const int r1   = r0 + 64;

    // ---- resident weights ----
    float wih0[IN_DIM], wih1[IN_DIM];
#pragma unroll
    for (int k = 0; k < 9; ++k) {
        ((float4*)wih0)[k] = ((const float4*)(W_ih + r0 * IN_DIM))[k];
        ((float4*)wih1)[k] = ((const float4*)(W_ih + r1 * IN_DIM))[k];
    }
    float whh0[HID], whh1[HID];
#pragma unroll
    for (int k = 0; k < 8; ++k) {
        ((float4*)whh0)[k] = ((const float4*)(W_hh + r0 * HID))[k];
        ((float4*)whh1)[k] = ((const float4*)(W_hh + r1 * HID))[k];
    }
    const v2f* w0 = (const v2f*)whh0;
    const v2f* w1 = (const v2f*)whh1;
    const v2f wx0a = ((const v2f*)wih0)[0], wx0b = ((const v2f*)wih0)[1];
    const v2f wx1a = ((const v2f*)wih1)[0], wx1b = ((const v2f*)wih1)[1];

    // collapse rank-1 y-embedding into per-row (u, bias)
    float u0 = 0.f, u1 = 0.f;
    float bias0 = b_ih[r0] + b_hh[r0], bias1 = b_ih[r1] + b_hh[r1];
#pragma unroll
    for (int k = 0; k < 32; ++k) {
        u0 += W_ye[k] * wih0[4 + k];  bias0 += b_ye[k] * wih0[4 + k];
        u1 += W_ye[k] * wih1[4 + k];  bias1 += b_ye[k] * wih1[4 + k];
    }

    // collapsed-attention constants (uniform values, per-lane regs)
    float A = 0.f, B = 0.f, C1 = 0.f, C2 = 0.f, C3 = 0.f, C4 = 0.f;
#pragma unroll
    for (int k = 0; k < 32; ++k) {
        const float wef = W_ef[k], bef = b_ef[k], wav = W_av[k];
        A  += wef * wav;           B  += bef * wav;
        C1 += wef * W_out[k];      C2 += bef * W_out[k];
        C3 += wef * W_out[32 + k]; C4 += bef * W_out[32 + k];
    }
    B  += b_av[0];
    C2 += b_out[0];
    const float bmu  = b_mu[0], bsig = b_sig[0];
    const float wmu_l  = p ? 0.f : W_mu[j];
    const float wsig_l = p ? 0.f : W_sig[j];
    // per-lane constants for tanh-via-sigmoid without selects
    const float sc_a = p ? 1.f : 2.f;      // arg scale
    const float sc_b = p ? 0.f : -1.f;     // result offset

    float h = 0.f, c = 0.f;

#define GATE_MATVEC(G0, G1, X01, X23, YT)                                      \
    {                                                                          \
        v2f a0 = {0.f, 0.f}, b0 = {0.f, 0.f};                                  \
        v2f a1 = {0.f, 0.f}, b1 = {0.f, 0.f};                                  \
        pk_fma_s(a0, wx0a, X01); pk_fma_s(b0, wx0b, X23);                      \
        pk_fma_s(a1, wx1a, X01); pk_fma_s(b1, wx1b, X23);                      \
        _Pragma("unroll")                                                      \
        for (int m = 0; m < 8; ++m) {                                          \
            const double hp = mk2(rdlane(h, 4 * m), rdlane(h, 4 * m + 2));     \
            pk_fma_s(a0, w0[m], hp);                                           \
            pk_fma_s(a1, w1[m], hp);                                           \
        }                                                                      \
        _Pragma("unroll")                                                      \
        for (int m = 0; m < 8; ++m) {                                          \
            const double hp = mk2(rdlane(h, 32 + 4 * m), rdlane(h, 34 + 4 * m));\
            pk_fma_s(b0, w0[8 + m], hp);                                       \
            pk_fma_s(b1, w1[8 + m], hp);                                       \
        }                                                                      \
        const v2f s0v = a0 + b0, s1v = a1 + b1;                                \
        G0 = fmaf(YT, u0, bias0) + (s0v.x + s0v.y);                            \
        G1 = fmaf(YT, u1, bias1) + (s1v.x + s1v.y);                            \
    }

#define LSTM_NONLIN(G0, G1)                                                    \
    {                                                                          \
        const float s0 = fsig(G0);                                             \
        const float sg = fsig((G1) * sc_a);                                    \
        const float s1 = fmaf(sg, sc_a, sc_b);                                 \
        const float f_sh = DPP0(s0, 0xB1, 0xF, 0xF, false);                    \
        const float o_sh = DPP0(s1, 0xB1, 0xF, 0xF, false);                    \
        c = f_sh * c + s0 * s1;                                                \
        h = o_sh * ftanh(c);                                                   \
    }

    // ---------- Phase A: t = 0..510 — LSTM cell only; outputs deferred ----------
    float4 xc = *(const float4*)(X);
    float  yc = y[0];
    float4 xn = *(const float4*)(X + F_IN);
    float  yn = y[1];
#pragma unroll 2
    for (int t = 0; t < S_LEN - 1; ++t) {
        const int tp = (t + 2 < S_LEN) ? t + 2 : S_LEN - 1;
        const float4 xf = *(const float4*)(X + tp * F_IN);
        const float  yf = y[tp];

        const double x01 = mk2(xc.x, xc.y), x23 = mk2(xc.z, xc.w);
        float g0, g1;
        GATE_MATVEC(g0, g1, x01, x23, yc);
        LSTM_NONLIN(g0, g1);

        if (!(lane & 1)) hist[t * HID + j] = h;   // even lanes hold true h

        xc = xn; yc = yn; xn = xf; yn = yf;
    }

    // ---------- Phase B: t = 511..575 — full step (feedback needed) ----------
    float ynext = 0.f;
    const float y511 = y[S_LEN - 1];
    // prefetch state (1 ahead)
    float4 xb = *(const float4*)(X + (S_LEN - 1) * F_IN);
    float  eb = eps[S_LEN - 1];
#pragma unroll 1
    for (int t = S_LEN - 1; t < T_LEN; ++t) {
        const int tp = (t + 1 < T_LEN) ? t + 1 : T_LEN - 1;
        const float* src = (tp < S_LEN) ? (X + tp * F_IN) : (Xf + (tp - S_LEN) * F_IN);
        const float4 xf = *(const float4*)src;
        const float  ef = eps[tp];

        const float yin = (t == S_LEN - 1) ? y511 : ynext;
        const double x01 = mk2(xb.x, xb.y), x23 = mk2(xb.z, xb.w);
        float g0, g1;
        GATE_MATVEC(g0, g1, x01, x23, yin);
        LSTM_NONLIN(g0, g1);

        // collapsed attention (exclusive prefix over elements j at even lanes)
        const float av   = __expf(h * A + B);
        const float av_e = p ? 0.f : av;
        const float avh  = av_e * h;
        float sP = av_e, sQ = avh;
        sP += DPP0(sP, 0x112, 0xF, 0xF, true);  sQ += DPP0(sQ, 0x112, 0xF, 0xF, true);
        sP += DPP0(sP, 0x114, 0xF, 0xF, true);  sQ += DPP0(sQ, 0x114, 0xF, 0xF, true);
        sP += DPP0(sP, 0x118, 0xF, 0xF, true);  sQ += DPP0(sQ, 0x118, 0xF, 0xF, true);
        float tP = DPP0(sP, 0x111, 0xF, 0xF, true), tQ = DPP0(sQ, 0x111, 0xF, 0xF, true);
        sP += DPP0(tP, 0x142, 0xA, 0xF, true);  sQ += DPP0(tQ, 0x142, 0xA, 0xF, true);
        tP = DPP0(sP, 0x111, 0xF, 0xF, true);   tQ = DPP0(sQ, 0x111, 0xF, 0xF, true);
        sP += DPP0(tP, 0x143, 0xC, 0xF, true);  sQ += DPP0(tQ, 0x143, 0xC, 0xF, true);

        const float P = sP - av_e, Q = sQ - avh;
        const float rden = frcp(P + 1e-9f);
        const float outv = ftanh(h * C1 + C2 + (Q * C3 + P * C4) * rden);

        // mu / sigma: DPP tree-reduce, total in lane 63
        float pm = outv * wmu_l, ps = outv * wsig_l;
        pm += DPP0(pm, 0xB1,  0xF, 0xF, false);  ps += DPP0(ps, 0xB1,  0xF, 0xF, false);
        pm += DPP0(pm, 0x4E,  0xF, 0xF, false);  ps += DPP0(ps, 0x4E,  0xF, 0xF, false);
        pm += DPP0(pm, 0x141, 0xF, 0xF, false);  ps += DPP0(ps, 0x141, 0xF, 0xF, false);
        pm += DPP0(pm, 0x140, 0xF, 0xF, false);  ps += DPP0(ps, 0x140, 0xF, 0xF, false);
        pm += DPP0(pm, 0x142, 0xA, 0xF, true);   ps += DPP0(ps, 0x142, 0xA, 0xF, true);
        pm += DPP0(pm, 0x143, 0xC, 0xF, true);   ps += DPP0(ps, 0x143, 0xC, 0xF, true);

        const float mu    = rdlane(pm, 63) + bmu;
        const float sigma = __logf(1.f + __expf(rdlane(ps, 63) + bsig)) + 1e-6f;
        const float ynew  = mu + sigma * eb;
        ynext = ynew;

        if (lane == 0) {
            out[HORIZON + t]         = mu;
            out[HORIZON + T_LEN + t] = sigma;
            if (t >= S_LEN - 1 && t < S_LEN - 1 + HORIZON)
                out[t - (S_LEN - 1)] = ynew;
        }

        xb = xf; eb = ef;
    }
#undef GATE_MATVEC
#undef LSTM_NONLIN
}

// ============ Kernel 2: parallel deferred outputs for t = 0..510 ============
__global__ __launch_bounds__(256) void deepar_par(
    const float* __restrict__ hist,
    const float* __restrict__ W_ef, const float* __restrict__ b_ef,
    const float* __restrict__ W_av, const float* __restrict__ b_av,
    const float* __restrict__ W_out, const float* __restrict__ b_out,
    const float* __restrict__ W_mu, const float* __restrict__ b_mu,
    const float* __restrict__ W_sig, const float* __restrict__ b_sig,
    float* __restrict__ out)
{
    const int gid = (blockIdx.x * 256 + threadIdx.x) >> 5;   // one step per 32 lanes
    const int l   = threadIdx.x & 31;
    if (gid >= S_LEN - 1) return;

    float A = 0.f, B = 0.f, C1 = 0.f, C2 = 0.f, C3 = 0.f, C4 = 0.f;
#pragma unroll
    for (int k = 0; k < 32; ++k) {
        const float wef = W_ef[k], bef = b_ef[k], wav = W_av[k];
        A  += wef * wav;           B  += bef * wav;
        C1 += wef * W_out[k];      C2 += bef * W_out[k];
        C3 += wef * W_out[32 + k]; C4 += bef * W_out[32 + k];
    }
    B  += b_av[0];
    C2 += b_out[0];

    const float hj  = hist[gid * HID + l];
    const float av  = __expf(hj * A + B);
    const float avh = av * hj;
    float sP = av, sQ = avh;
#pragma unroll
    for (int d = 1; d < 32; d <<= 1) {
        const float pP = __shfl_up(sP, d, 32);
        const float pQ = __shfl_up(sQ, d, 32);
        if (l >= d) { sP += pP; sQ += pQ; }
    }
    const float P = sP - av, Q = sQ - avh;
    const float rden = frcp(P + 1e-9f);
    const float outv = ftanh(hj * C1 + C2 + (Q * C3 + P * C4) * rden);

    float pm = outv * W_mu[l], ps = outv * W_sig[l];
#pragma unroll
    for (int m = 16; m >= 1; m >>= 1) {
        pm += __shfl_xor(pm, m, 32);
        ps += __shfl_xor(ps, m, 32);
    }
    if (l == 0) {
        out[HORIZON + gid]         = pm + b_mu[0];
        out[HORIZON + T_LEN + gid] = __logf(1.f + __expf(ps + b_sig[0])) + 1e-6f;
    }
}

extern "C" void kernel_launch(void* const* d_in, const int* in_sizes, int n_in,
                              void* d_out, int out_size, void* d_ws, size_t ws_size,
                              hipStream_t stream) {
    float* hist = (float*)d_ws;   // (S_LEN-1) x HID floats

    deepar_seq<<<1, 64, 0, stream>>>(
        (const float*)d_in[0],  (const float*)d_in[1],  (const float*)d_in[2],
        (const float*)d_in[3],  (const float*)d_in[4],  (const float*)d_in[5],
        (const float*)d_in[6],  (const float*)d_in[7],  (const float*)d_in[8],
        (const float*)d_in[9],  (const float*)d_in[10], (const float*)d_in[11],
        (const float*)d_in[12], (const float*)d_in[13], (const float*)d_in[14],
        (const float*)d_in[15], (const float*)d_in[16], (const float*)d_in[17],
        (const float*)d_in[18], (const float*)d_in[19], (float*)d_out, hist);

    const int groups = S_LEN - 1;
    const int blocks = (groups * 32 + 255) / 256;
    deepar_par<<<blocks, 256, 0, stream>>>(
        hist,
        (const float*)d_in[10], (const float*)d_in[11],
        (const float*)d_in[12], (const float*)d_in[13],
        (const float*)d_in[14], (const float*)d_in[15],
        (const float*)d_in[16], (const float*)d_in[17],
        (const float*)d_in[18], (const float*)d_in[19], (float*)d_out);
}

// Round 5
// 244.965 us; speedup vs baseline: 1.4367x; 1.4367x over previous
//
#include <hip/hip_runtime.h>
#include <math.h>
#include <stdint.h>

#define S_LEN   512
#define HORIZON 64
#define T_LEN   (S_LEN + HORIZON)
#define F_IN    4
#define IN_DIM  36   // F_IN + E
#define HID     32

typedef float v2f __attribute__((ext_vector_type(2)));

__device__ __forceinline__ float frcp(float x) { return __builtin_amdgcn_rcpf(x); }
__device__ __forceinline__ float fsig(float x) { return frcp(1.f + __expf(-x)); }
__device__ __forceinline__ float ftanh(float x) {
    float e = __expf(2.f * x);
    return (e - 1.f) * frcp(e + 1.f);
}
__device__ __forceinline__ float rdlane(float v, int l) {
    return __int_as_float(__builtin_amdgcn_readlane(__float_as_int(v), l));
}
__device__ __forceinline__ void pk_fma(v2f& acc, v2f a, v2f b) {
    asm("v_pk_fma_f32 %0, %1, %2, %0" : "+v"(acc) : "v"(a), "v"(b));
}

// DPP move with old=0.
#define DPP0(x, ctrl, rmask, bmask, bc) \
    __int_as_float(__builtin_amdgcn_update_dpp(0, __float_as_int(x), (ctrl), (rmask), (bmask), (bc)))

// ============ Kernel 1: the sequential recurrence (one wave) ============
// Interleaved layout: lane 2j+p: p==0 -> rows i[j], g[j]; p==1 -> rows f[j], o[j].
// h[j], c[j] valid at even lanes (odd lanes carry bounded garbage, never read).
__global__ __launch_bounds__(64, 1) void deepar_seq(
    const float* __restrict__ X,    const float* __restrict__ y,
    const float* __restrict__ Xf,   const float* __restrict__ eps,
    const float* __restrict__ W_ye, const float* __restrict__ b_ye,
    const float* __restrict__ W_ih, const float* __restrict__ W_hh,
    const float* __restrict__ b_ih, const float* __restrict__ b_hh,
    const float* __restrict__ W_ef, const float* __restrict__ b_ef,
    const float* __restrict__ W_av, const float* __restrict__ b_av,
    const float* __restrict__ W_out, const float* __restrict__ b_out,
    const float* __restrict__ W_mu, const float* __restrict__ b_mu,
    const float* __restrict__ W_sig, const float* __restrict__ b_sig,
    float* __restrict__ out, float* __restrict__ hist2)
{
    const int lane = threadIdx.x;
    const int j    = lane >> 1;
    const int p    = lane & 1;
    const int r0   = j + 32 * p;
    const int r1   = r0 + 64;

    // ---- LDS staging of all per-step inputs + h broadcast line ----
    __shared__ __align__(16) float Xall[T_LEN * F_IN];   // X then Xf, (t,4)
    __shared__ __align__(16) float ys[S_LEN];
    __shared__ __align__(16) float epss[T_LEN];
    __shared__ __align__(16) float h_lds[HID];

#pragma unroll
    for (int k = 0; k < 8; ++k)   // X: 512 float4
        ((float4*)Xall)[lane + 64 * k] = ((const float4*)X)[lane + 64 * k];
    ((float4*)Xall)[512 + lane] = ((const float4*)Xf)[lane];   // Xf: 64 float4
#pragma unroll
    for (int k = 0; k < 2; ++k)   // y: 128 float4
        ((float4*)ys)[lane + 64 * k] = ((const float4*)y)[lane + 64 * k];
#pragma unroll
    for (int k = 0; k < 2; ++k)   // eps: first 128 of 144 float4
        ((float4*)epss)[lane + 64 * k] = ((const float4*)eps)[lane + 64 * k];
    if (lane < 16)
        ((float4*)epss)[lane + 128] = ((const float4*)eps)[lane + 128];

    // ---- resident weights ----
    float wih0[IN_DIM], wih1[IN_DIM];
#pragma unroll
    for (int k = 0; k < 9; ++k) {
        ((float4*)wih0)[k] = ((const float4*)(W_ih + r0 * IN_DIM))[k];
        ((float4*)wih1)[k] = ((const float4*)(W_ih + r1 * IN_DIM))[k];
    }
    float whh0[HID], whh1[HID];
#pragma unroll
    for (int k = 0; k < 8; ++k) {
        ((float4*)whh0)[k] = ((const float4*)(W_hh + r0 * HID))[k];
        ((float4*)whh1)[k] = ((const float4*)(W_hh + r1 * HID))[k];
    }
    const v2f* w0 = (const v2f*)whh0;
    const v2f* w1 = (const v2f*)whh1;
    const v2f wx0a = ((const v2f*)wih0)[0], wx0b = ((const v2f*)wih0)[1];
    const v2f wx1a = ((const v2f*)wih1)[0], wx1b = ((const v2f*)wih1)[1];

    // collapse rank-1 y-embedding into per-row (u, bias)
    float u0 = 0.f, u1 = 0.f;
    float bias0 = b_ih[r0] + b_hh[r0], bias1 = b_ih[r1] + b_hh[r1];
#pragma unroll
    for (int k = 0; k < 32; ++k) {
        u0 += W_ye[k] * wih0[4 + k];  bias0 += b_ye[k] * wih0[4 + k];
        u1 += W_ye[k] * wih1[4 + k];  bias1 += b_ye[k] * wih1[4 + k];
    }

    // collapsed-attention constants (uniform values)
    float A = 0.f, B = 0.f, C1 = 0.f, C2 = 0.f, C3 = 0.f, C4 = 0.f;
#pragma unroll
    for (int k = 0; k < 32; ++k) {
        const float wef = W_ef[k], bef = b_ef[k], wav = W_av[k];
        A  += wef * wav;           B  += bef * wav;
        C1 += wef * W_out[k];      C2 += bef * W_out[k];
        C3 += wef * W_out[32 + k]; C4 += bef * W_out[32 + k];
    }
    B  += b_av[0];
    C2 += b_out[0];
    const float bmu  = b_mu[0], bsig = b_sig[0];
    const float wmu_l  = p ? 0.f : W_mu[j];
    const float wsig_l = p ? 0.f : W_sig[j];
    const float sc_a = p ? 1.f : 2.f;      // tanh-via-sigmoid without selects
    const float sc_b = p ? 0.f : -1.f;

    __syncthreads();   // one barrier after staging (single wave; cheap)

    float h = 0.f, c = 0.f;

#define GATE_MATVEC(G0, G1, XV, YT)                                        \
    {                                                                      \
        const v2f x01 = {(XV).x, (XV).y}, x23 = {(XV).z, (XV).w};          \
        v2f a00 = wx0a * x01, a01 = wx0b * x23;                            \
        v2f a10 = wx1a * x01, a11 = wx1b * x23;                            \
        _Pragma("unroll")                                                  \
        for (int k = 0; k < 8; ++k) {                                      \
            const float4 hq = ((const float4*)h_lds)[k];                   \
            const v2f hlo = {hq.x, hq.y}, hhi = {hq.z, hq.w};              \
            pk_fma(a00, w0[2 * k], hlo);  pk_fma(a01, w0[2 * k + 1], hhi); \
            pk_fma(a10, w1[2 * k], hlo);  pk_fma(a11, w1[2 * k + 1], hhi); \
        }                                                                  \
        const v2f s0v = a00 + a01, s1v = a10 + a11;                        \
        G0 = fmaf((YT), u0, bias0) + (s0v.x + s0v.y);                      \
        G1 = fmaf((YT), u1, bias1) + (s1v.x + s1v.y);                      \
    }

#define LSTM_NONLIN(G0, G1)                                                \
    {                                                                      \
        const float s0 = fsig(G0);                                         \
        const float sg = fsig((G1) * sc_a);                                \
        const float s1 = fmaf(sg, sc_a, sc_b);                             \
        const float f_sh = DPP0(s0, 0xB1, 0xF, 0xF, false);                \
        const float o_sh = DPP0(s1, 0xB1, 0xF, 0xF, false);                \
        c = f_sh * c + s0 * s1;                                            \
        h = o_sh * ftanh(c);                                               \
    }

    // ---------- Phase A: t = 0..510 — LSTM cell only; outputs deferred ----------
#pragma unroll 4
    for (int t = 0; t < S_LEN - 1; ++t) {
        const float4 xv = ((const float4*)Xall)[t];
        const float  yt = ys[t];
        if (!p) h_lds[j] = h;

        float g0, g1;
        GATE_MATVEC(g0, g1, xv, yt);
        LSTM_NONLIN(g0, g1);

        hist2[t * 64 + lane] = h;   // all lanes store; even entries valid
    }

    // ---------- Phase B: t = 511..575 — full step (feedback needed) ----------
    float ynext = 0.f;
    const float y511 = ys[S_LEN - 1];
#pragma unroll 1
    for (int t = S_LEN - 1; t < T_LEN; ++t) {
        const float4 xv   = ((const float4*)Xall)[t];
        const float eps_t = epss[t];
        const float yin   = (t == S_LEN - 1) ? y511 : ynext;
        if (!p) h_lds[j] = h;

        float g0, g1;
        GATE_MATVEC(g0, g1, xv, yin);
        LSTM_NONLIN(g0, g1);

        // collapsed attention (exclusive prefix over elements j at even lanes)
        const float av   = __expf(h * A + B);
        const float av_e = p ? 0.f : av;
        const float avh  = av_e * h;
        float sP = av_e, sQ = avh;
        sP += DPP0(sP, 0x112, 0xF, 0xF, true);  sQ += DPP0(sQ, 0x112, 0xF, 0xF, true);
        sP += DPP0(sP, 0x114, 0xF, 0xF, true);  sQ += DPP0(sQ, 0x114, 0xF, 0xF, true);
        sP += DPP0(sP, 0x118, 0xF, 0xF, true);  sQ += DPP0(sQ, 0x118, 0xF, 0xF, true);
        float tP = DPP0(sP, 0x111, 0xF, 0xF, true), tQ = DPP0(sQ, 0x111, 0xF, 0xF, true);
        sP += DPP0(tP, 0x142, 0xA, 0xF, true);  sQ += DPP0(tQ, 0x142, 0xA, 0xF, true);
        tP = DPP0(sP, 0x111, 0xF, 0xF, true);   tQ = DPP0(sQ, 0x111, 0xF, 0xF, true);
        sP += DPP0(tP, 0x143, 0xC, 0xF, true);  sQ += DPP0(tQ, 0x143, 0xC, 0xF, true);

        const float P = sP - av_e, Q = sQ - avh;
        const float rden = frcp(P + 1e-9f);
        const float outv = ftanh(h * C1 + C2 + (Q * C3 + P * C4) * rden);

        // mu / sigma: DPP tree-reduce, total in lane 63
        float pm = outv * wmu_l, ps = outv * wsig_l;
        pm += DPP0(pm, 0xB1,  0xF, 0xF, false);  ps += DPP0(ps, 0xB1,  0xF, 0xF, false);
        pm += DPP0(pm, 0x4E,  0xF, 0xF, false);  ps += DPP0(ps, 0x4E,  0xF, 0xF, false);
        pm += DPP0(pm, 0x141, 0xF, 0xF, false);  ps += DPP0(ps, 0x141, 0xF, 0xF, false);
        pm += DPP0(pm, 0x140, 0xF, 0xF, false);  ps += DPP0(ps, 0x140, 0xF, 0xF, false);
        pm += DPP0(pm, 0x142, 0xA, 0xF, true);   ps += DPP0(ps, 0x142, 0xA, 0xF, true);
        pm += DPP0(pm, 0x143, 0xC, 0xF, true);   ps += DPP0(ps, 0x143, 0xC, 0xF, true);

        const float mu    = rdlane(pm, 63) + bmu;
        const float sigma = __logf(1.f + __expf(rdlane(ps, 63) + bsig)) + 1e-6f;
        const float ynew  = mu + sigma * eps_t;
        ynext = ynew;

        if (lane == 0) {
            out[HORIZON + t]         = mu;
            out[HORIZON + T_LEN + t] = sigma;
            if (t >= S_LEN - 1 && t < S_LEN - 1 + HORIZON)
                out[t - (S_LEN - 1)] = ynew;
        }
    }
#undef GATE_MATVEC
#undef LSTM_NONLIN
}

// ============ Kernel 2: parallel deferred outputs for t = 0..510 ============
__global__ __launch_bounds__(256) void deepar_par(
    const float* __restrict__ hist2,
    const float* __restrict__ W_ef, const float* __restrict__ b_ef,
    const float* __restrict__ W_av, const float* __restrict__ b_av,
    const float* __restrict__ W_out, const float* __restrict__ b_out,
    const float* __restrict__ W_mu, const float* __restrict__ b_mu,
    const float* __restrict__ W_sig, const float* __restrict__ b_sig,
    float* __restrict__ out)
{
    const int gid = (blockIdx.x * 256 + threadIdx.x) >> 5;   // one step per 32 lanes
    const int l   = threadIdx.x & 31;
    if (gid >= S_LEN - 1) return;

    float A = 0.f, B = 0.f, C1 = 0.f, C2 = 0.f, C3 = 0.f, C4 = 0.f;
#pragma unroll
    for (int k = 0; k < 32; ++k) {
        const float wef = W_ef[k], bef = b_ef[k], wav = W_av[k];
        A  += wef * wav;           B  += bef * wav;
        C1 += wef * W_out[k];      C2 += bef * W_out[k];
        C3 += wef * W_out[32 + k]; C4 += bef * W_out[32 + k];
    }
    B  += b_av[0];
    C2 += b_out[0];

    const float hj  = hist2[gid * 64 + 2 * l];   // even entries hold true h
    const float av  = __expf(hj * A + B);
    const float avh = av * hj;
    float sP = av, sQ = avh;
#pragma unroll
    for (int d = 1; d < 32; d <<= 1) {
        const float pP = __shfl_up(sP, d, 32);
        const float pQ = __shfl_up(sQ, d, 32);
        if (l >= d) { sP += pP; sQ += pQ; }
    }
    const float P = sP - av, Q = sQ - avh;
    const float rden = frcp(P + 1e-9f);
    const float outv = ftanh(hj * C1 + C2 + (Q * C3 + P * C4) * rden);

    float pm = outv * W_mu[l], ps = outv * W_sig[l];
#pragma unroll
    for (int m = 16; m >= 1; m >>= 1) {
        pm += __shfl_xor(pm, m, 32);
        ps += __shfl_xor(ps, m, 32);
    }
    if (l == 0) {
        out[HORIZON + gid]         = pm + b_mu[0];
        out[HORIZON + T_LEN + gid] = __logf(1.f + __expf(ps + b_sig[0])) + 1e-6f;
    }
}

extern "C" void kernel_launch(void* const* d_in, const int* in_sizes, int n_in,
                              void* d_out, int out_size, void* d_ws, size_t ws_size,
                              hipStream_t stream) {
    float* hist2 = (float*)d_ws;   // (S_LEN-1) x 64 floats

    deepar_seq<<<1, 64, 0, stream>>>(
        (const float*)d_in[0],  (const float*)d_in[1],  (const float*)d_in[2],
        (const float*)d_in[3],  (const float*)d_in[4],  (const float*)d_in[5],
        (const float*)d_in[6],  (const float*)d_in[7],  (const float*)d_in[8],
        (const float*)d_in[9],  (const float*)d_in[10], (const float*)d_in[11],
        (const float*)d_in[12], (const float*)d_in[13], (const float*)d_in[14],
        (const float*)d_in[15], (const float*)d_in[16], (const float*)d_in[17],
        (const float*)d_in[18], (const float*)d_in[19], (float*)d_out, hist2);

    const int groups = S_LEN - 1;
    const int blocks = (groups * 32 + 255) / 256;
    deepar_par<<<blocks, 256, 0, stream>>>(
        hist2,
        (const float*)d_in[10], (const float*)d_in[11],
        (const float*)d_in[12], (const float*)d_in[13],
        (const float*)d_in[14], (const float*)d_in[15],
        (const float*)d_in[16], (const float*)d_in[17],
        (const float*)d_in[18], (const float*)d_in[19], (float*)d_out);
}